// Round 1
// baseline (5912.606 us; speedup 1.0000x reference)
//
#include <hip/hip_runtime.h>
#include <hip/hip_bf16.h>

#define D128 128

typedef __attribute__((ext_vector_type(8))) short bf16x8;
typedef __attribute__((ext_vector_type(4))) float f32x4;

__device__ __forceinline__ short f2bf(float f) {
  union { float f; unsigned u; } v; v.f = f;
  unsigned r = v.u + 0x7FFFu + ((v.u >> 16) & 1u);  // RNE
  return (short)(r >> 16);
}

// ---- generic f32 -> bf16 weight conversion ----
__global__ __launch_bounds__(256) void cvt_bf16_k(const float* __restrict__ in,
                                                  short* __restrict__ out, int n) {
  int i = blockIdx.x * 256 + threadIdx.x;
  if (i < n) out[i] = f2bf(in[i]);
}

// ---- per-dst edge counts ----
__global__ __launch_bounds__(256) void count_k(const int* __restrict__ dst,
                                               int* __restrict__ cnt, int nE) {
  int i = blockIdx.x * 256 + threadIdx.x;
  if (i < nE) atomicAdd(&cnt[dst[i]], 1);
}

__global__ __launch_bounds__(256) void inv_k(const int* __restrict__ cnt,
                                             float* __restrict__ inv, int n) {
  int i = blockIdx.x * 256 + threadIdx.x;
  if (i < n) { int c = cnt[i]; inv[i] = 1.0f / (float)(c > 1 ? c : 1); }
}

// ---- scatter-add: 32 lanes per edge, float4 per lane, 4 hw f32 atomics ----
template <int RELU>
__global__ __launch_bounds__(256) void scatter_k(const float* __restrict__ xsrc,
                                                 const int* __restrict__ eidx,
                                                 float* __restrict__ agg, int nE) {
  int g = (int)(((size_t)blockIdx.x * 256 + threadIdx.x) >> 5);
  int lane = threadIdx.x & 31;
  if (g >= nE) return;
  int s = eidx[g];
  int d = eidx[nE + g];
  float4 v = *(const float4*)(xsrc + (size_t)s * D128 + lane * 4);
  if (RELU) {
    v.x = fmaxf(v.x, 0.f); v.y = fmaxf(v.y, 0.f);
    v.z = fmaxf(v.z, 0.f); v.w = fmaxf(v.w, 0.f);
  }
  float* ap = agg + (size_t)d * D128 + lane * 4;
  unsafeAtomicAdd(ap + 0, v.x);
  unsafeAtomicAdd(ap + 1, v.y);
  unsafeAtomicAdd(ap + 2, v.z);
  unsafeAtomicAdd(ap + 3, v.w);
}

// ---- fused SAGE node transform: c = (agg*inv)@Wl^T + bl + [relu](x)@Wr^T,
//      then L2-normalize per node, then out = / += result.
//      One wave per 16-node tile, full 128-wide output, MFMA 16x16x32 bf16.
template <int RELU_X, int ACC>
__global__ __launch_bounds__(256)
void sage_apply(const float* __restrict__ agg, const float* __restrict__ inv,
                const float* __restrict__ xd, const short* __restrict__ Wl,
                const float* __restrict__ bias, const short* __restrict__ Wr,
                float* __restrict__ out, int ntiles) {
  int w = threadIdx.x >> 6;
  int lane = threadIdx.x & 63;
  int tile = blockIdx.x * 4 + w;
  if (tile >= ntiles) return;
  int r = lane & 15;        // A-row / B-col / D-col index
  int kh = lane >> 4;       // k-chunk selector
  size_t n0 = (size_t)tile * 16;
  int nodeA = (int)n0 + r;
  float iv = inv[nodeA];

  f32x4 acc[8];
#pragma unroll
  for (int t = 0; t < 8; t++) acc[t] = (f32x4){0.f, 0.f, 0.f, 0.f};

  const float* ap = agg + (size_t)nodeA * D128 + kh * 8;
  const float* xp = xd + (size_t)nodeA * D128 + kh * 8;

#pragma unroll
  for (int kk = 0; kk < 4; kk++) {
    int d0 = kk * 32;
    f32x4 a0 = *(const f32x4*)(ap + d0);
    f32x4 a1 = *(const f32x4*)(ap + d0 + 4);
    f32x4 x0 = *(const f32x4*)(xp + d0);
    f32x4 x1 = *(const f32x4*)(xp + d0 + 4);
    if (RELU_X) {
#pragma unroll
      for (int j = 0; j < 4; j++) { x0[j] = fmaxf(x0[j], 0.f); x1[j] = fmaxf(x1[j], 0.f); }
    }
    bf16x8 af, xf;
#pragma unroll
    for (int j = 0; j < 4; j++) {
      af[j]     = f2bf(a0[j] * iv);
      af[j + 4] = f2bf(a1[j] * iv);
      xf[j]     = f2bf(x0[j]);
      xf[j + 4] = f2bf(x1[j]);
    }
#pragma unroll
    for (int t = 0; t < 8; t++) {
      const short* wlp = Wl + (size_t)(t * 16 + r) * D128 + d0 + kh * 8;
      const short* wrp = Wr + (size_t)(t * 16 + r) * D128 + d0 + kh * 8;
      bf16x8 bwl = *(const bf16x8*)wlp;
      bf16x8 bwr = *(const bf16x8*)wrp;
      acc[t] = __builtin_amdgcn_mfma_f32_16x16x32_bf16(af, bwl, acc[t], 0, 0, 0);
      acc[t] = __builtin_amdgcn_mfma_f32_16x16x32_bf16(xf, bwr, acc[t], 0, 0, 0);
    }
  }

  // epilogue: bias, squared-sum per node (row = kh*4+q), 16-lane reduce, normalize, store
  float s[4] = {0.f, 0.f, 0.f, 0.f};
#pragma unroll
  for (int t = 0; t < 8; t++) {
    float bv = bias[t * 16 + r];
#pragma unroll
    for (int q = 0; q < 4; q++) {
      float c = acc[t][q] + bv;
      acc[t][q] = c;
      s[q] += c * c;
    }
  }
#pragma unroll
  for (int off = 1; off < 16; off <<= 1) {
    s[0] += __shfl_xor(s[0], off);
    s[1] += __shfl_xor(s[1], off);
    s[2] += __shfl_xor(s[2], off);
    s[3] += __shfl_xor(s[3], off);
  }
  float rn[4];
#pragma unroll
  for (int q = 0; q < 4; q++) rn[q] = 1.0f / fmaxf(sqrtf(s[q]), 1e-12f);

#pragma unroll
  for (int t = 0; t < 8; t++) {
#pragma unroll
    for (int q = 0; q < 4; q++) {
      size_t node = n0 + kh * 4 + q;
      float vv = acc[t][q] * rn[q];
      float* op = out + node * D128 + t * 16 + r;
      if (ACC) *op += vv; else *op = vv;
    }
  }
}

// ---- classifier: 32 lanes per node, C=2 ----
__global__ __launch_bounds__(256)
void clf_k(const float* __restrict__ h, const float* __restrict__ W,
           const float* __restrict__ b, float* __restrict__ out, int n) {
  int g = (int)(((size_t)blockIdx.x * 256 + threadIdx.x) >> 5);
  int lane = threadIdx.x & 31;
  if (g >= n) return;
  float4 v = *(const float4*)(h + (size_t)g * D128 + lane * 4);
  float4 w0 = *(const float4*)(W + lane * 4);
  float4 w1 = *(const float4*)(W + D128 + lane * 4);
  float p0 = v.x * w0.x + v.y * w0.y + v.z * w0.z + v.w * w0.w;
  float p1 = v.x * w1.x + v.y * w1.y + v.z * w1.z + v.w * w1.w;
#pragma unroll
  for (int off = 16; off; off >>= 1) {
    p0 += __shfl_xor(p0, off);
    p1 += __shfl_xor(p1, off);
  }
  if (lane == 0) {
    out[(size_t)g * 2 + 0] = p0 + b[0];
    out[(size_t)g * 2 + 1] = p1 + b[1];
  }
}

extern "C" void kernel_launch(void* const* d_in, const int* in_sizes, int n_in,
                              void* d_out, int out_size, void* d_ws, size_t ws_size,
                              hipStream_t stream) {
  const float* emb_app = (const float*)d_in[0];
  const float* emb_mer = (const float*)d_in[1];
  const float* emb_dev = (const float*)d_in[2];
  const float* c1Wl = (const float*)d_in[3];
  const float* c1bl = (const float*)d_in[4];
  const float* c1Wr = (const float*)d_in[5];
  const float* c2Wl = (const float*)d_in[6];
  const float* c2bl = (const float*)d_in[7];
  const float* c2Wr = (const float*)d_in[8];
  const float* clfW = (const float*)d_in[9];
  const float* clfb = (const float*)d_in[10];
  const int* e0 = (const int*)d_in[11];
  const int* e1 = (const int*)d_in[12];
  const int* e2 = (const int*)d_in[13];
  const int* e3 = (const int*)d_in[14];

  const int NA = in_sizes[0] / D128;
  const int NM = in_sizes[1] / D128;
  const int ND = in_sizes[2] / D128;
  const int E = in_sizes[11] / 2;
  float* out = (float*)d_out;

  char* wsb = (char*)d_ws;
  size_t off = 0;
  auto alloc = [&](size_t bytes) -> char* {
    char* p = wsb + off;
    off += (bytes + 511) & ~(size_t)511;
    return p;
  };
  short* wl1 = (short*)alloc((size_t)4 * 16384 * 2);
  short* wr1 = (short*)alloc((size_t)4 * 16384 * 2);
  short* wl2 = (short*)alloc((size_t)4 * 16384 * 2);
  short* wr2 = (short*)alloc((size_t)4 * 16384 * 2);
  int ncnt = NM + NA + ND + NA;
  int* cnt = (int*)alloc((size_t)ncnt * 4);
  float* inv = (float*)alloc((size_t)ncnt * 4);
  float* agg = (float*)alloc((size_t)NA * D128 * 4);
  float* h1a = (float*)alloc((size_t)NA * D128 * 4);
  float* h1m = (float*)alloc((size_t)NM * D128 * 4);
  float* h1d = (float*)alloc((size_t)ND * D128 * 4);
  float* h2a = (float*)alloc((size_t)NA * D128 * 4);
  (void)ws_size;  // requires ~389 MB of workspace

  int* cnt0 = cnt;                 float* inv0 = inv;
  int* cnt1 = cnt + NM;            float* inv1 = inv + NM;
  int* cnt2 = cnt + NM + NA;       float* inv2 = inv + NM + NA;
  int* cnt3 = cnt + NM + NA + ND;  float* inv3 = inv + NM + NA + ND;

  // weights -> bf16
  int nw = 4 * 16384;
  cvt_bf16_k<<<(nw + 255) / 256, 256, 0, stream>>>(c1Wl, wl1, nw);
  cvt_bf16_k<<<(nw + 255) / 256, 256, 0, stream>>>(c1Wr, wr1, nw);
  cvt_bf16_k<<<(nw + 255) / 256, 256, 0, stream>>>(c2Wl, wl2, nw);
  cvt_bf16_k<<<(nw + 255) / 256, 256, 0, stream>>>(c2Wr, wr2, nw);

  // degree counts (shared across both layers)
  hipMemsetAsync(cnt, 0, (size_t)ncnt * 4, stream);
  int cgrid = (E + 255) / 256;
  count_k<<<cgrid, 256, 0, stream>>>(e0 + E, cnt0, E);
  count_k<<<cgrid, 256, 0, stream>>>(e1 + E, cnt1, E);
  count_k<<<cgrid, 256, 0, stream>>>(e2 + E, cnt2, E);
  count_k<<<cgrid, 256, 0, stream>>>(e3 + E, cnt3, E);
  inv_k<<<(ncnt + 255) / 256, 256, 0, stream>>>(cnt, inv, ncnt);

  int sgrid = (int)(((size_t)E * 32 + 255) / 256);
  auto agrid = [](int ntiles) { return (ntiles + 3) / 4; };

  // ---- layer 1 ----
  // k0: app -> mer
  hipMemsetAsync(agg, 0, (size_t)NM * D128 * 4, stream);
  scatter_k<0><<<sgrid, 256, 0, stream>>>(emb_app, e0, agg, E);
  sage_apply<0, 0><<<agrid(NM / 16), 256, 0, stream>>>(agg, inv0, emb_mer,
      wl1 + 0 * 16384, c1bl + 0 * D128, wr1 + 0 * 16384, h1m, NM / 16);
  // k1: mer -> app
  hipMemsetAsync(agg, 0, (size_t)NA * D128 * 4, stream);
  scatter_k<0><<<sgrid, 256, 0, stream>>>(emb_mer, e1, agg, E);
  sage_apply<0, 0><<<agrid(NA / 16), 256, 0, stream>>>(agg, inv1, emb_app,
      wl1 + 1 * 16384, c1bl + 1 * D128, wr1 + 1 * 16384, h1a, NA / 16);
  // k2: app -> dev
  hipMemsetAsync(agg, 0, (size_t)ND * D128 * 4, stream);
  scatter_k<0><<<sgrid, 256, 0, stream>>>(emb_app, e2, agg, E);
  sage_apply<0, 0><<<agrid(ND / 16), 256, 0, stream>>>(agg, inv2, emb_dev,
      wl1 + 2 * 16384, c1bl + 2 * D128, wr1 + 2 * 16384, h1d, ND / 16);
  // k3: dev -> app (accumulate into h1a)
  hipMemsetAsync(agg, 0, (size_t)NA * D128 * 4, stream);
  scatter_k<0><<<sgrid, 256, 0, stream>>>(emb_dev, e3, agg, E);
  sage_apply<0, 1><<<agrid(NA / 16), 256, 0, stream>>>(agg, inv3, emb_app,
      wl1 + 3 * 16384, c1bl + 3 * D128, wr1 + 3 * 16384, h1a, NA / 16);

  // ---- layer 2 (only dst=app matters for the classifier) ----
  // k1: mer -> app, sources relu(h1m), lin_r input relu(h1a)
  hipMemsetAsync(agg, 0, (size_t)NA * D128 * 4, stream);
  scatter_k<1><<<sgrid, 256, 0, stream>>>(h1m, e1, agg, E);
  sage_apply<1, 0><<<agrid(NA / 16), 256, 0, stream>>>(agg, inv1, h1a,
      wl2 + 1 * 16384, c2bl + 1 * D128, wr2 + 1 * 16384, h2a, NA / 16);
  // k3: dev -> app
  hipMemsetAsync(agg, 0, (size_t)NA * D128 * 4, stream);
  scatter_k<1><<<sgrid, 256, 0, stream>>>(h1d, e3, agg, E);
  sage_apply<1, 1><<<agrid(NA / 16), 256, 0, stream>>>(agg, inv3, h1a,
      wl2 + 3 * 16384, c2bl + 3 * D128, wr2 + 3 * 16384, h2a, NA / 16);

  // ---- classifier ----
  clf_k<<<(int)(((size_t)NA * 32 + 255) / 256), 256, 0, stream>>>(h2a, clfW, clfb, out, NA);
}

// Round 2
// 1440.532 us; speedup vs baseline: 4.1045x; 4.1045x over previous
//
#include <hip/hip_runtime.h>
#include <hip/hip_bf16.h>

#define D128 128

typedef __attribute__((ext_vector_type(8))) short bf16x8;
typedef __attribute__((ext_vector_type(4))) float f32x4;

__device__ __forceinline__ short f2bf(float f) {
  union { float f; unsigned u; } v; v.f = f;
  unsigned r = v.u + 0x7FFFu + ((v.u >> 16) & 1u);  // RNE
  return (short)(r >> 16);
}

// ---- generic f32 -> bf16 weight conversion ----
__global__ __launch_bounds__(256) void cvt_bf16_k(const float* __restrict__ in,
                                                  short* __restrict__ out, int n) {
  int i = blockIdx.x * 256 + threadIdx.x;
  if (i < n) out[i] = f2bf(in[i]);
}

// ---- per-dst edge counts ----
__global__ __launch_bounds__(256) void count_k(const int* __restrict__ dst,
                                               int* __restrict__ cnt, int nE) {
  int i = blockIdx.x * 256 + threadIdx.x;
  if (i < nE) atomicAdd(&cnt[dst[i]], 1);
}

__global__ __launch_bounds__(256) void inv_k(const int* __restrict__ cnt,
                                             float* __restrict__ inv, int n) {
  int i = blockIdx.x * 256 + threadIdx.x;
  if (i < n) { int c = cnt[i]; inv[i] = 1.0f / (float)(c > 1 ? c : 1); }
}

// ---- scan stage 1: per-256-block sums of cnt ----
__device__ __forceinline__ int wave_incl_scan(int v, int lane) {
#pragma unroll
  for (int off = 1; off < 64; off <<= 1) {
    int y = __shfl_up(v, off);
    if (lane >= off) v += y;
  }
  return v;
}

__global__ __launch_bounds__(256) void scan1_k(const int* __restrict__ cnt,
                                               int* __restrict__ bsum, int n) {
  int b = blockIdx.x, tid = threadIdx.x;
  int i = b * 256 + tid;
  int v = (i < n) ? cnt[i] : 0;
  int lane = tid & 63, wid = tid >> 6;
  __shared__ int ws[4];
  int s = wave_incl_scan(v, lane);
  if (lane == 63) ws[wid] = s;
  __syncthreads();
  if (tid == 0) bsum[b] = ws[0] + ws[1] + ws[2] + ws[3];
}

// ---- scan stage 2: block base = sum(bsum[0..b)), then in-block exclusive
//      scan; writes ofs (kept) and cur (mutable cursor copy) ----
__global__ __launch_bounds__(256) void scan2_k(const int* __restrict__ cnt,
                                               const int* __restrict__ bsum,
                                               int* __restrict__ ofs,
                                               int* __restrict__ cur, int n) {
  int b = blockIdx.x, tid = threadIdx.x;
  int lane = tid & 63, wid = tid >> 6;
  __shared__ int wsA[4], wsB[4];
  // block base
  int p = 0;
  for (int j = tid; j < b; j += 256) p += bsum[j];
#pragma unroll
  for (int off = 32; off; off >>= 1) p += __shfl_xor(p, off);
  if (lane == 0) wsA[wid] = p;
  __syncthreads();
  int base = wsA[0] + wsA[1] + wsA[2] + wsA[3];
  // in-block exclusive scan
  int i = b * 256 + tid;
  int v = (i < n) ? cnt[i] : 0;
  int s = wave_incl_scan(v, lane);
  if (lane == 63) wsB[wid] = s;
  __syncthreads();
  int woff = 0;
  for (int w = 0; w < wid; w++) woff += wsB[w];
  int excl = base + woff + s - v;
  if (i < n) { ofs[i] = excl; cur[i] = excl; }
}

// ---- bucket fill: counting-sort edges by dst (int atomics only) ----
__global__ __launch_bounds__(256) void fill_k(const int* __restrict__ eidx,
                                              int* __restrict__ cur,
                                              int* __restrict__ bucket,
                                              int base, int nE) {
  int i = blockIdx.x * 256 + threadIdx.x;
  if (i >= nE) return;
  int s = eidx[i];
  int d = eidx[nE + i];
  int pos = atomicAdd(&cur[base + d], 1);
  bucket[pos] = s;
}

// ---- CSR gather-aggregate: one wave per dst node, float2 per lane ----
template <int RELU>
__global__ __launch_bounds__(256)
void agg_csr_k(const float* __restrict__ xsrc, const int* __restrict__ ofs,
               const int* __restrict__ cnt, const int* __restrict__ bucket,
               float* __restrict__ agg, int n) {
  int w = (int)(((size_t)blockIdx.x * 256 + threadIdx.x) >> 6);
  int lane = threadIdx.x & 63;
  if (w >= n) return;
  int beg = ofs[w];
  int c = cnt[w];
  float ax = 0.f, ay = 0.f;
  for (int j = 0; j < c; j++) {
    int s = bucket[beg + j];
    float2 v = *(const float2*)(xsrc + (size_t)s * D128 + lane * 2);
    if (RELU) { v.x = fmaxf(v.x, 0.f); v.y = fmaxf(v.y, 0.f); }
    ax += v.x; ay += v.y;
  }
  float2 o; o.x = ax; o.y = ay;
  *(float2*)(agg + (size_t)w * D128 + lane * 2) = o;
}

// ---- fused SAGE node transform: c = (agg*inv)@Wl^T + bl + [relu](x)@Wr^T,
//      then L2-normalize per node, then out = / += result. ----
template <int RELU_X, int ACC>
__global__ __launch_bounds__(256)
void sage_apply(const float* __restrict__ agg, const float* __restrict__ inv,
                const float* __restrict__ xd, const short* __restrict__ Wl,
                const float* __restrict__ bias, const short* __restrict__ Wr,
                float* __restrict__ out, int ntiles) {
  int w = threadIdx.x >> 6;
  int lane = threadIdx.x & 63;
  int tile = blockIdx.x * 4 + w;
  if (tile >= ntiles) return;
  int r = lane & 15;
  int kh = lane >> 4;
  size_t n0 = (size_t)tile * 16;
  int nodeA = (int)n0 + r;
  float iv = inv[nodeA];

  f32x4 acc[8];
#pragma unroll
  for (int t = 0; t < 8; t++) acc[t] = (f32x4){0.f, 0.f, 0.f, 0.f};

  const float* ap = agg + (size_t)nodeA * D128 + kh * 8;
  const float* xp = xd + (size_t)nodeA * D128 + kh * 8;

#pragma unroll
  for (int kk = 0; kk < 4; kk++) {
    int d0 = kk * 32;
    f32x4 a0 = *(const f32x4*)(ap + d0);
    f32x4 a1 = *(const f32x4*)(ap + d0 + 4);
    f32x4 x0 = *(const f32x4*)(xp + d0);
    f32x4 x1 = *(const f32x4*)(xp + d0 + 4);
    if (RELU_X) {
#pragma unroll
      for (int j = 0; j < 4; j++) { x0[j] = fmaxf(x0[j], 0.f); x1[j] = fmaxf(x1[j], 0.f); }
    }
    bf16x8 af, xf;
#pragma unroll
    for (int j = 0; j < 4; j++) {
      af[j]     = f2bf(a0[j] * iv);
      af[j + 4] = f2bf(a1[j] * iv);
      xf[j]     = f2bf(x0[j]);
      xf[j + 4] = f2bf(x1[j]);
    }
#pragma unroll
    for (int t = 0; t < 8; t++) {
      const short* wlp = Wl + (size_t)(t * 16 + r) * D128 + d0 + kh * 8;
      const short* wrp = Wr + (size_t)(t * 16 + r) * D128 + d0 + kh * 8;
      bf16x8 bwl = *(const bf16x8*)wlp;
      bf16x8 bwr = *(const bf16x8*)wrp;
      acc[t] = __builtin_amdgcn_mfma_f32_16x16x32_bf16(af, bwl, acc[t], 0, 0, 0);
      acc[t] = __builtin_amdgcn_mfma_f32_16x16x32_bf16(xf, bwr, acc[t], 0, 0, 0);
    }
  }

  float s[4] = {0.f, 0.f, 0.f, 0.f};
#pragma unroll
  for (int t = 0; t < 8; t++) {
    float bv = bias[t * 16 + r];
#pragma unroll
    for (int q = 0; q < 4; q++) {
      float c = acc[t][q] + bv;
      acc[t][q] = c;
      s[q] += c * c;
    }
  }
#pragma unroll
  for (int off = 1; off < 16; off <<= 1) {
    s[0] += __shfl_xor(s[0], off);
    s[1] += __shfl_xor(s[1], off);
    s[2] += __shfl_xor(s[2], off);
    s[3] += __shfl_xor(s[3], off);
  }
  float rn[4];
#pragma unroll
  for (int q = 0; q < 4; q++) rn[q] = 1.0f / fmaxf(sqrtf(s[q]), 1e-12f);

#pragma unroll
  for (int t = 0; t < 8; t++) {
#pragma unroll
    for (int q = 0; q < 4; q++) {
      size_t node = n0 + kh * 4 + q;
      float vv = acc[t][q] * rn[q];
      float* op = out + node * D128 + t * 16 + r;
      if (ACC) *op += vv; else *op = vv;
    }
  }
}

// ---- classifier: 32 lanes per node, C=2 ----
__global__ __launch_bounds__(256)
void clf_k(const float* __restrict__ h, const float* __restrict__ W,
           const float* __restrict__ b, float* __restrict__ out, int n) {
  int g = (int)(((size_t)blockIdx.x * 256 + threadIdx.x) >> 5);
  int lane = threadIdx.x & 31;
  if (g >= n) return;
  float4 v = *(const float4*)(h + (size_t)g * D128 + lane * 4);
  float4 w0 = *(const float4*)(W + lane * 4);
  float4 w1 = *(const float4*)(W + D128 + lane * 4);
  float p0 = v.x * w0.x + v.y * w0.y + v.z * w0.z + v.w * w0.w;
  float p1 = v.x * w1.x + v.y * w1.y + v.z * w1.z + v.w * w1.w;
#pragma unroll
  for (int off = 16; off; off >>= 1) {
    p0 += __shfl_xor(p0, off);
    p1 += __shfl_xor(p1, off);
  }
  if (lane == 0) {
    out[(size_t)g * 2 + 0] = p0 + b[0];
    out[(size_t)g * 2 + 1] = p1 + b[1];
  }
}

extern "C" void kernel_launch(void* const* d_in, const int* in_sizes, int n_in,
                              void* d_out, int out_size, void* d_ws, size_t ws_size,
                              hipStream_t stream) {
  const float* emb_app = (const float*)d_in[0];
  const float* emb_mer = (const float*)d_in[1];
  const float* emb_dev = (const float*)d_in[2];
  const float* c1Wl = (const float*)d_in[3];
  const float* c1bl = (const float*)d_in[4];
  const float* c1Wr = (const float*)d_in[5];
  const float* c2Wl = (const float*)d_in[6];
  const float* c2bl = (const float*)d_in[7];
  const float* c2Wr = (const float*)d_in[8];
  const float* clfW = (const float*)d_in[9];
  const float* clfb = (const float*)d_in[10];
  const int* e0 = (const int*)d_in[11];
  const int* e1 = (const int*)d_in[12];
  const int* e2 = (const int*)d_in[13];
  const int* e3 = (const int*)d_in[14];

  const int NA = in_sizes[0] / D128;
  const int NM = in_sizes[1] / D128;
  const int ND = in_sizes[2] / D128;
  const int E = in_sizes[11] / 2;
  float* out = (float*)d_out;

  char* wsb = (char*)d_ws;
  size_t off = 0;
  auto alloc = [&](size_t bytes) -> char* {
    char* p = wsb + off;
    off += (bytes + 511) & ~(size_t)511;
    return p;
  };
  short* wl1 = (short*)alloc((size_t)4 * 16384 * 2);
  short* wr1 = (short*)alloc((size_t)4 * 16384 * 2);
  short* wl2 = (short*)alloc((size_t)4 * 16384 * 2);
  short* wr2 = (short*)alloc((size_t)4 * 16384 * 2);
  int ncnt = NM + NA + ND + NA;
  int nb = (ncnt + 255) / 256;
  int* cnt = (int*)alloc((size_t)ncnt * 4);
  float* inv = (float*)alloc((size_t)ncnt * 4);
  int* ofs = (int*)alloc((size_t)ncnt * 4);
  int* cur = (int*)alloc((size_t)ncnt * 4);
  int* bsum = (int*)alloc((size_t)nb * 4);
  int* bucket = (int*)alloc((size_t)4 * E * 4);
  float* agg = (float*)alloc((size_t)NA * D128 * 4);
  float* h1a = (float*)alloc((size_t)NA * D128 * 4);
  float* h1m = (float*)alloc((size_t)NM * D128 * 4);
  float* h1d = (float*)alloc((size_t)ND * D128 * 4);
  float* h2a = (float*)alloc((size_t)NA * D128 * 4);
  (void)ws_size;  // ~400 MB of workspace

  // per-type bases within the concatenated dst-count array
  int b0 = 0, b1 = NM, b2 = NM + NA, b3 = NM + NA + ND;

  // weights -> bf16
  int nw = 4 * 16384;
  cvt_bf16_k<<<(nw + 255) / 256, 256, 0, stream>>>(c1Wl, wl1, nw);
  cvt_bf16_k<<<(nw + 255) / 256, 256, 0, stream>>>(c1Wr, wr1, nw);
  cvt_bf16_k<<<(nw + 255) / 256, 256, 0, stream>>>(c2Wl, wl2, nw);
  cvt_bf16_k<<<(nw + 255) / 256, 256, 0, stream>>>(c2Wr, wr2, nw);

  // degree counts (shared across both layers)
  hipMemsetAsync(cnt, 0, (size_t)ncnt * 4, stream);
  int cgrid = (E + 255) / 256;
  count_k<<<cgrid, 256, 0, stream>>>(e0 + E, cnt + b0, E);
  count_k<<<cgrid, 256, 0, stream>>>(e1 + E, cnt + b1, E);
  count_k<<<cgrid, 256, 0, stream>>>(e2 + E, cnt + b2, E);
  count_k<<<cgrid, 256, 0, stream>>>(e3 + E, cnt + b3, E);
  inv_k<<<(ncnt + 255) / 256, 256, 0, stream>>>(cnt, inv, ncnt);

  // CSR build: exclusive scan over concatenated cnt, then bucket fill
  scan1_k<<<nb, 256, 0, stream>>>(cnt, bsum, ncnt);
  scan2_k<<<nb, 256, 0, stream>>>(cnt, bsum, ofs, cur, ncnt);
  fill_k<<<cgrid, 256, 0, stream>>>(e0, cur, bucket, b0, E);
  fill_k<<<cgrid, 256, 0, stream>>>(e1, cur, bucket, b1, E);
  fill_k<<<cgrid, 256, 0, stream>>>(e2, cur, bucket, b2, E);
  fill_k<<<cgrid, 256, 0, stream>>>(e3, cur, bucket, b3, E);

  auto wgrid = [](int n) { return (n + 3) / 4; };     // one wave per node
  auto agrid = [](int ntiles) { return (ntiles + 3) / 4; };

  // ---- layer 1 ----
  // k0: app -> mer
  agg_csr_k<0><<<wgrid(NM), 256, 0, stream>>>(emb_app, ofs + b0, cnt + b0, bucket, agg, NM);
  sage_apply<0, 0><<<agrid(NM / 16), 256, 0, stream>>>(agg, inv + b0, emb_mer,
      wl1 + 0 * 16384, c1bl + 0 * D128, wr1 + 0 * 16384, h1m, NM / 16);
  // k1: mer -> app
  agg_csr_k<0><<<wgrid(NA), 256, 0, stream>>>(emb_mer, ofs + b1, cnt + b1, bucket, agg, NA);
  sage_apply<0, 0><<<agrid(NA / 16), 256, 0, stream>>>(agg, inv + b1, emb_app,
      wl1 + 1 * 16384, c1bl + 1 * D128, wr1 + 1 * 16384, h1a, NA / 16);
  // k2: app -> dev
  agg_csr_k<0><<<wgrid(ND), 256, 0, stream>>>(emb_app, ofs + b2, cnt + b2, bucket, agg, ND);
  sage_apply<0, 0><<<agrid(ND / 16), 256, 0, stream>>>(agg, inv + b2, emb_dev,
      wl1 + 2 * 16384, c1bl + 2 * D128, wr1 + 2 * 16384, h1d, ND / 16);
  // k3: dev -> app (accumulate into h1a)
  agg_csr_k<0><<<wgrid(NA), 256, 0, stream>>>(emb_dev, ofs + b3, cnt + b3, bucket, agg, NA);
  sage_apply<0, 1><<<agrid(NA / 16), 256, 0, stream>>>(agg, inv + b3, emb_app,
      wl1 + 3 * 16384, c1bl + 3 * D128, wr1 + 3 * 16384, h1a, NA / 16);

  // ---- layer 2 (only dst=app feeds the classifier) ----
  // k1: mer -> app, sources relu(h1m), lin_r input relu(h1a)
  agg_csr_k<1><<<wgrid(NA), 256, 0, stream>>>(h1m, ofs + b1, cnt + b1, bucket, agg, NA);
  sage_apply<1, 0><<<agrid(NA / 16), 256, 0, stream>>>(agg, inv + b1, h1a,
      wl2 + 1 * 16384, c2bl + 1 * D128, wr2 + 1 * 16384, h2a, NA / 16);
  // k3: dev -> app
  agg_csr_k<1><<<wgrid(NA), 256, 0, stream>>>(h1d, ofs + b3, cnt + b3, bucket, agg, NA);
  sage_apply<1, 1><<<agrid(NA / 16), 256, 0, stream>>>(agg, inv + b3, h1a,
      wl2 + 3 * 16384, c2bl + 3 * D128, wr2 + 3 * 16384, h2a, NA / 16);

  // ---- classifier ----
  clf_k<<<(int)(((size_t)NA * 32 + 255) / 256), 256, 0, stream>>>(h2a, clfW, clfb, out, NA);
}